// Round 7
// baseline (362.594 us; speedup 1.0000x reference)
//
#include <hip/hip_runtime.h>
#include <hip/hip_bf16.h>
#include <math.h>

typedef short bf16x8 __attribute__((ext_vector_type(8)));
typedef unsigned short us8 __attribute__((ext_vector_type(8)));
typedef unsigned short us4 __attribute__((ext_vector_type(4)));
typedef float f32x2 __attribute__((ext_vector_type(2)));
typedef float f32x4 __attribute__((ext_vector_type(4)));
typedef float f32x16 __attribute__((ext_vector_type(16)));
typedef unsigned int u32;
typedef unsigned int u32x4 __attribute__((ext_vector_type(4)));

__device__ __forceinline__ unsigned short f2bf(float f) {
  unsigned int u = __builtin_bit_cast(unsigned int, f);
  u += 0x7fffu + ((u >> 16) & 1u);
  return (unsigned short)(u >> 16);
}

__device__ __forceinline__ void gload16(const void* g, void* l) {
  __builtin_amdgcn_global_load_lds(
      (const __attribute__((address_space(1))) unsigned int*)g,
      (__attribute__((address_space(3))) unsigned int*)l, 16, 0, 0);
}

// ---- fused fp32 -> bf16 conversion for q_in/k_in/v_in ----
__global__ __launch_bounds__(256) void k_conv3(const float* __restrict__ i0,
                                               const float* __restrict__ i1,
                                               const float* __restrict__ i2,
                                               unsigned short* __restrict__ o0,
                                               unsigned short* __restrict__ o1,
                                               unsigned short* __restrict__ o2) {
  int bid = blockIdx.x;
  int g = bid >> 13;                 // 8192 blocks per tensor
  const float* in = g == 0 ? i0 : g == 1 ? i1 : i2;
  unsigned short* out = g == 0 ? o0 : g == 1 ? o1 : o2;
  int i = (bid & 8191) * 256 + threadIdx.x;
  float4 v = ((const float4*)in)[i];
  us4 o;
  o[0] = f2bf(v.x); o[1] = f2bf(v.y); o[2] = f2bf(v.z); o[3] = f2bf(v.w);
  ((us4*)out)[i] = o;
}

// ---- fused weight packing: g<3: [H,D,DK]->Wt[N][K]; g==3: wo [K][N]->WoT[N][K] ----
__global__ __launch_bounds__(256) void k_pack4(const float* __restrict__ wq,
                                               const float* __restrict__ wk,
                                               const float* __restrict__ wv,
                                               const float* __restrict__ wo,
                                               unsigned short* __restrict__ Wqt,
                                               unsigned short* __restrict__ Wkt,
                                               unsigned short* __restrict__ Wvt,
                                               unsigned short* __restrict__ Wot) {
  __shared__ float tl[64][65];
  int bid = blockIdx.x;
  int g = bid >> 8;
  int bl = bid & 255;
  int tid = threadIdx.x;
  if (g < 3) {
    const float* w = g == 0 ? wq : g == 1 ? wk : wv;
    unsigned short* wt = g == 0 ? Wqt : g == 1 ? Wkt : Wvt;
    int h = bl >> 4, dt = bl & 15;
#pragma unroll
    for (int i = 0; i < 16; ++i) {
      int idx = i * 256 + tid;
      int d = idx >> 6, c = idx & 63;
      tl[c][d] = w[h * 65536 + (dt * 64 + d) * 64 + c];
    }
    __syncthreads();
#pragma unroll
    for (int i = 0; i < 16; ++i) {
      int idx = i * 256 + tid;
      int c = idx >> 6, d = idx & 63;
      wt[(h * 64 + c) * 1024 + dt * 64 + d] = f2bf(tl[c][d]);
    }
  } else {
    int kt = bl >> 4, nt = bl & 15;
#pragma unroll
    for (int i = 0; i < 16; ++i) {
      int idx = i * 256 + tid;
      int k = idx >> 6, n = idx & 63;
      tl[n][k] = wo[(kt * 64 + k) * 1024 + nt * 64 + n];
    }
    __syncthreads();
#pragma unroll
    for (int i = 0; i < 16; ++i) {
      int idx = i * 256 + tid;
      int n = idx >> 6, k = idx & 63;
      Wot[(nt * 64 + n) * 1024 + kt * 64 + k] = f2bf(tl[n][k]);
    }
  }
}

// ---- bf16 GEMM body, stage-ahead double-buffered (1 barrier / K-step) ----
template<int OUT_BF16>
__device__ __forceinline__ void gemm_body(const unsigned short* __restrict__ A,
                                          const unsigned short* __restrict__ Bt,
                                          const float* __restrict__ bias,
                                          void* __restrict__ Cout, float scale,
                                          int bid) {
  __shared__ unsigned short As[2][128 * 32];
  __shared__ unsigned short Bs[2][128 * 32];
  const int tid = threadIdx.x;
  const int l = tid & 63, w = tid >> 6;
  const int wr = w >> 1, wc = w & 1;
  bid = (bid & 7) * 64 + (bid >> 3);    // XCD swizzle (512 = 8*64)
  const int bx = bid & 7;
  const int by = bid >> 3;
  const long brow = (long)by * 128;
  const int bcol = bx * 128;
  const int lr = l & 15, lg = l >> 4;
  f32x4 acc[4][4] = {};

  const char* aS0 = (const char*)(A + (brow + (tid >> 2)) * 1024 + (tid & 3) * 8);
  const char* aS1 = aS0 + 131072;
  const char* bS0 = (const char*)(Bt + (long)(bcol + (tid >> 2)) * 1024 + (tid & 3) * 8);
  const char* bS1 = bS0 + 131072;
  char* aD = (char*)&As[0][0] + w * 1024;
  char* bD = (char*)&Bs[0][0] + w * 1024;
  const char* aP = (const char*)&As[0][0] + ((wr * 64 + lr) * 32 + lg * 8) * 2;
  const char* bP = (const char*)&Bs[0][0] + ((wc * 64 + lr) * 32 + lg * 8) * 2;

  auto stage = [&](int curbuf) {
    gload16(aS0, aD + curbuf * 8192);
    gload16(aS1, aD + curbuf * 8192 + 4096);
    gload16(bS0, bD + curbuf * 8192);
    gload16(bS1, bD + curbuf * 8192 + 4096);
    aS0 += 64; aS1 += 64; bS0 += 64; bS1 += 64;
  };

  stage(0);
  for (int kk = 0; kk < 16; ++kk) {
#pragma unroll
    for (int cur = 0; cur < 2; ++cur) {
      int k0 = kk * 64 + cur * 32;
      __syncthreads();
      if (k0 + 32 < 1024) stage(cur ^ 1);
      bf16x8 af[4], bfr[4];
#pragma unroll
      for (int m = 0; m < 4; ++m)
        af[m] = *(const bf16x8*)(aP + cur * 8192 + m * 1024);
#pragma unroll
      for (int n = 0; n < 4; ++n)
        bfr[n] = *(const bf16x8*)(bP + cur * 8192 + n * 1024);
#pragma unroll
      for (int m = 0; m < 4; ++m)
#pragma unroll
        for (int n = 0; n < 4; ++n)
          acc[m][n] = __builtin_amdgcn_mfma_f32_16x16x32_bf16(af[m], bfr[n], acc[m][n], 0, 0, 0);
    }
  }

#pragma unroll
  for (int m = 0; m < 4; ++m) {
#pragma unroll
    for (int n = 0; n < 4; ++n) {
      int col = bcol + wc * 64 + n * 16 + lr;
      float bia = bias[col];
#pragma unroll
      for (int i = 0; i < 4; ++i) {
        long row = brow + wr * 64 + m * 16 + lg * 4 + i;
        float v = (acc[m][n][i] + bia) * scale;
        if (OUT_BF16) ((unsigned short*)Cout)[row * 1024 + col] = f2bf(v);
        else          ((float*)Cout)[row * 1024 + col] = v;
      }
    }
  }
}

__global__ __launch_bounds__(256) void k_gemm_qkv(const unsigned short* __restrict__ Aq,
                                                  const unsigned short* __restrict__ Ak,
                                                  const unsigned short* __restrict__ Av,
                                                  const unsigned short* __restrict__ Wqt,
                                                  const unsigned short* __restrict__ Wkt,
                                                  const unsigned short* __restrict__ Wvt,
                                                  const float* __restrict__ bq,
                                                  const float* __restrict__ bk,
                                                  const float* __restrict__ bv,
                                                  unsigned short* __restrict__ Qa,
                                                  unsigned short* __restrict__ Ka,
                                                  unsigned short* __restrict__ Va,
                                                  float qscale) {
  int g = blockIdx.x >> 9;
  int bl = blockIdx.x & 511;
  const unsigned short* A  = g == 0 ? Aq  : g == 1 ? Ak  : Av;
  const unsigned short* Bt = g == 0 ? Wqt : g == 1 ? Wkt : Wvt;
  const float* bia         = g == 0 ? bq  : g == 1 ? bk  : bv;
  unsigned short* C        = g == 0 ? Qa  : g == 1 ? Ka  : Va;
  gemm_body<1>(A, Bt, bia, C, g == 0 ? qscale : 1.0f, bl);
}

__global__ __launch_bounds__(256) void k_gemm_wo(const unsigned short* __restrict__ A,
                                                 const unsigned short* __restrict__ Bt,
                                                 const float* __restrict__ bias,
                                                 float* __restrict__ Cout) {
  gemm_body<0>(A, Bt, bias, Cout, 1.0f, blockIdx.x);
}

// ---- transpose V_all [8192,1024] -> Vt [bh][c=64][s=2048] (bf16) ----
__global__ __launch_bounds__(256) void k_transpose_v(const unsigned short* __restrict__ V,
                                                     unsigned short* __restrict__ Vt) {
  __shared__ unsigned short tile[64][72];
  int bid = blockIdx.x;
  int bh = bid >> 5, st = bid & 31;
  int b = bh >> 4, h = bh & 15;
  int tid = threadIdx.x;
#pragma unroll
  for (int i = 0; i < 2; ++i) {
    int idx = i * 256 + tid;
    int r = idx >> 3, ch = idx & 7;
    us8 v = *(const us8*)&V[((long)(b * 2048 + st * 64 + r)) * 1024 + h * 64 + ch * 8];
#pragma unroll
    for (int j = 0; j < 8; ++j) tile[ch * 8 + j][r] = v[j];
  }
  __syncthreads();
#pragma unroll
  for (int i = 0; i < 2; ++i) {
    int idx = i * 256 + tid;
    int c = idx >> 3, ch = idx & 7;
    us8 v;
#pragma unroll
    for (int j = 0; j < 8; ++j) v[j] = tile[c][ch * 8 + j];
    *(us8*)&Vt[(long)bh * 131072 + (long)c * 2048 + st * 64 + ch * 8] = v;
  }
}

// ---- flash attention v6: 64 q-rows/wave, interleaved half-tile schedule ----
// Per h2 half: {kf loads -> QK chains (qs0,qs1) -> exp2/pack -> PV of this half}.
// PV(h2=0) VALU/MFMA overlaps QK(h2=1); pa frags die per-half (lower VGPR peak).
// LDS: K0@0,V0@8192,K1@16384,V1@24576 (dbuf). No-max exp2 softmax (Q pre-scaled
// log2e/8); in-register P via cvt_pk+permlane32. Grid: 64 bh x 8 = 512, XCD-swz.
__global__ __launch_bounds__(256) void k_attn6(const unsigned short* __restrict__ Q,
                                               const unsigned short* __restrict__ K,
                                               const unsigned short* __restrict__ Vt,
                                               unsigned short* __restrict__ AO) {
  __shared__ unsigned short KV[4][4096];
  __shared__ float Li[4][64];
  const int tid = threadIdx.x;
  const int l = tid & 63, w = tid >> 6;
  const int l31 = l & 31, hi = l >> 5;
  int bid0 = blockIdx.x;
  int bid = (bid0 & 7) * 64 + (bid0 >> 3);   // XCD swizzle (512 = 8*64)
  const int bh = bid >> 3, qt0 = bid & 7;
  const int b = bh >> 4, h = bh & 15;
  const unsigned short* Qb = Q + (long)b * 2048 * 1024 + h * 64;
  const unsigned short* Kb = K + (long)b * 2048 * 1024 + h * 64;
  const unsigned short* Vb = Vt + (long)bh * 131072;   // [64 c][2048 s]
  const int qbase = qt0 * 256 + w * 64;

  // persistent Q fragments, 2 q-sets (rows qbase+l31 and qbase+32+l31)
  bf16x8 qf0[4], qf1[4];
#pragma unroll
  for (int c = 0; c < 4; ++c) {
    qf0[c] = *(const bf16x8*)&Qb[(long)(qbase + l31) * 1024 + c * 16 + hi * 8];
    qf1[c] = *(const bf16x8*)&Qb[(long)(qbase + 32 + l31) * 1024 + c * 16 + hi * 8];
  }

  f32x16 acc00 = {}, acc01 = {}, acc10 = {}, acc11 = {};
  f32x16 z16 = {};
  f32x2 liA0 = {0.f, 0.f}, liB0 = {0.f, 0.f};
  f32x2 liA1 = {0.f, 0.f}, liB1 = {0.f, 0.f};
  const int rsw = (l31 & 7) << 4;

  const char* pb[4];
#pragma unroll
  for (int c = 0; c < 4; ++c)
    pb[c] = (const char*)&KV[0][0] + l31 * 128 + ((c * 32 + hi * 16) ^ rsw);

  // staging pointers (pre-swizzled source, linear LDS dest)
  const int sch = tid & 7, srw = tid >> 3;
  const int ssw = (sch * 16) ^ ((srw & 7) << 4);
  const char* ks0 = (const char*)Kb + (long)srw * 2048 + ssw;
  const char* ks1 = ks0 + 65536;
  const char* vs0 = (const char*)Vb + (long)srw * 4096 + ssw;
  const char* vs1 = vs0 + 131072;
  char* dK = (char*)&KV[0][0] + w * 1024;
  char* dV = dK + 8192;

  auto stage = [&](int buf) {
    gload16(ks0, dK + buf * 16384);
    gload16(ks1, dK + buf * 16384 + 4096);
    gload16(vs0, dV + buf * 16384);
    gload16(vs1, dV + buf * 16384 + 4096);
    ks0 += 131072; ks1 += 131072;
    vs0 += 128;    vs1 += 128;
  };

  stage(0);
  for (int it = 0; it < 16; ++it) {
#pragma unroll
    for (int cur = 0; cur < 2; ++cur) {
      __syncthreads();                       // drains staging of cur
      if (it < 15 || cur == 0) stage(cur ^ 1);

#pragma unroll
      for (int h2 = 0; h2 < 2; ++h2) {
        // K fragments of this half (shared by both q-sets)
        bf16x8 kf[4];
#pragma unroll
        for (int c = 0; c < 4; ++c)
          kf[c] = *(const bf16x8*)(pb[c] + cur * 16384 + h2 * 4096);
        // two independent QK^T chains
        f32x16 s0 = __builtin_amdgcn_mfma_f32_32x32x16_bf16(kf[0], qf0[0], z16, 0, 0, 0);
        f32x16 s1 = __builtin_amdgcn_mfma_f32_32x32x16_bf16(kf[0], qf1[0], z16, 0, 0, 0);
#pragma unroll
        for (int c = 1; c < 4; ++c) {
          s0 = __builtin_amdgcn_mfma_f32_32x32x16_bf16(kf[c], qf0[c], s0, 0, 0, 0);
          s1 = __builtin_amdgcn_mfma_f32_32x32x16_bf16(kf[c], qf1[c], s1, 0, 0, 0);
        }
        // softmax + pack (both q-sets), P frags for this half only
        bf16x8 pa0[2], pa1[2];
#pragma unroll
        for (int qs = 0; qs < 2; ++qs) {
          const f32x16& s = qs == 0 ? s0 : s1;
          float p[16];
#pragma unroll
          for (int r = 0; r < 16; ++r) p[r] = __builtin_amdgcn_exp2f(s[r]);
#pragma unroll
          for (int g = 0; g < 4; ++g) {
            f32x2 pa; pa[0] = p[4 * g]; pa[1] = p[4 * g + 1];
            f32x2 pc; pc[0] = p[4 * g + 2]; pc[1] = p[4 * g + 3];
            if (qs == 0) { liA0 += pa; liB0 += pc; }
            else         { liA1 += pa; liB1 += pc; }
          }
          u32 wg[4][2];
#pragma unroll
          for (int g = 0; g < 4; ++g) {
            asm("v_cvt_pk_bf16_f32 %0, %1, %2" : "=v"(wg[g][0]) : "v"(p[4 * g]), "v"(p[4 * g + 1]));
            asm("v_cvt_pk_bf16_f32 %0, %1, %2" : "=v"(wg[g][1]) : "v"(p[4 * g + 2]), "v"(p[4 * g + 3]));
          }
#pragma unroll
          for (int sub = 0; sub < 2; ++sub) {
            u32 x0 = wg[2 * sub][0], y0 = wg[2 * sub + 1][0];
            u32 x1 = wg[2 * sub][1], y1 = wg[2 * sub + 1][1];
            asm("v_permlane32_swap_b32 %0, %1" : "+v"(x0), "+v"(y0));
            asm("v_permlane32_swap_b32 %0, %1" : "+v"(x1), "+v"(y1));
            u32x4 fw; fw[0] = x0; fw[1] = x1; fw[2] = y0; fw[3] = y1;
            if (qs == 0) pa0[sub] = __builtin_bit_cast(bf16x8, fw);
            else         pa1[sub] = __builtin_bit_cast(bf16x8, fw);
          }
        }
        // PV for this half: t-chunks ck = h2*2 + {0,1}; vf shared across q-sets
#pragma unroll
        for (int k2 = 0; k2 < 2; ++k2) {
          const int ck = h2 * 2 + k2;
          bf16x8 vf0 = *(const bf16x8*)(pb[ck] + cur * 16384 + 8192);
          bf16x8 vf1 = *(const bf16x8*)(pb[ck] + cur * 16384 + 8192 + 4096);
          acc00 = __builtin_amdgcn_mfma_f32_32x32x16_bf16(pa0[k2], vf0, acc00, 0, 0, 0);
          acc01 = __builtin_amdgcn_mfma_f32_32x32x16_bf16(pa0[k2], vf1, acc01, 0, 0, 0);
          acc10 = __builtin_amdgcn_mfma_f32_32x32x16_bf16(pa1[k2], vf0, acc10, 0, 0, 0);
          acc11 = __builtin_amdgcn_mfma_f32_32x32x16_bf16(pa1[k2], vf1, acc11, 0, 0, 0);
        }
      }
    }
  }

  // epilogue
  float li0 = liA0[0] + liA0[1] + liB0[0] + liB0[1];
  float li1 = liA1[0] + liA1[1] + liB1[0] + liB1[1];
  li0 += __shfl_xor(li0, 32);
  li1 += __shfl_xor(li1, 32);
  if (hi == 0) { Li[w][l31] = 1.f / li0; Li[w][32 + l31] = 1.f / li1; }
#pragma unroll
  for (int qs = 0; qs < 2; ++qs)
#pragma unroll
    for (int ct = 0; ct < 2; ++ct) {
      const f32x16& a = qs == 0 ? (ct == 0 ? acc00 : acc01) : (ct == 0 ? acc10 : acc11);
#pragma unroll
      for (int r = 0; r < 16; ++r) {
        int qrow = (r & 3) + 8 * (r >> 2) + 4 * hi;
        float inv = Li[w][qs * 32 + qrow];
        long row = (long)b * 2048 + qbase + qs * 32 + qrow;
        int col = h * 64 + ct * 32 + l31;
        AO[row * 1024 + col] = f2bf(a[r] * inv);
      }
    }
}

extern "C" void kernel_launch(void* const* d_in, const int* in_sizes, int n_in,
                              void* d_out, int out_size, void* d_ws, size_t ws_size,
                              hipStream_t stream) {
  (void)in_sizes; (void)n_in; (void)out_size; (void)ws_size;
  const float* q_in = (const float*)d_in[0];
  const float* k_in = (const float*)d_in[1];
  const float* v_in = (const float*)d_in[2];
  const float* wq   = (const float*)d_in[3];
  const float* bq   = (const float*)d_in[4];
  const float* wk   = (const float*)d_in[5];
  const float* bk   = (const float*)d_in[6];
  const float* wv   = (const float*)d_in[7];
  const float* bv   = (const float*)d_in[8];
  const float* wo   = (const float*)d_in[9];
  const float* bo   = (const float*)d_in[10];

  char* ws = (char*)d_ws;
  const size_t SZA = (size_t)8192 * 1024 * 2;   // 16 MiB per [8192,1024] bf16
  unsigned short* Aq  = (unsigned short*)(ws);
  unsigned short* Ak  = (unsigned short*)(ws + SZA);
  unsigned short* Av  = (unsigned short*)(ws + 2 * SZA);
  unsigned short* Qa  = (unsigned short*)(ws + 3 * SZA);
  unsigned short* Ka  = (unsigned short*)(ws + 4 * SZA);
  unsigned short* Va  = (unsigned short*)(ws + 5 * SZA);
  unsigned short* Wqt = (unsigned short*)(ws + 6 * SZA);
  unsigned short* Wkt = Wqt + 1048576;
  unsigned short* Wvt = Wkt + 1048576;
  unsigned short* Wot = Wvt + 1048576;
  unsigned short* Vtr = Ak;   // Ak dead after K projection GEMM
  unsigned short* AO  = Aq;   // Aq dead after Q projection GEMM

  const float QSCALE = 0.1803368801111204f;  // log2(e)/8 -> exp2-domain softmax

  k_conv3<<<24576, 256, 0, stream>>>(q_in, k_in, v_in, Aq, Ak, Av);
  k_pack4<<<1024, 256, 0, stream>>>(wq, wk, wv, wo, Wqt, Wkt, Wvt, Wot);
  k_gemm_qkv<<<1536, 256, 0, stream>>>(Aq, Ak, Av, Wqt, Wkt, Wvt, bq, bk, bv,
                                       Qa, Ka, Va, QSCALE);
  k_transpose_v<<<2048, 256, 0, stream>>>(Va, Vtr);
  k_attn6<<<512, 256, 0, stream>>>(Qa, Ka, Vtr, AO);
  k_gemm_wo<<<512, 256, 0, stream>>>(AO, Wot, bo, (float*)d_out);
}

// Round 8
// 362.314 us; speedup vs baseline: 1.0008x; 1.0008x over previous
//
#include <hip/hip_runtime.h>
#include <hip/hip_bf16.h>
#include <math.h>

typedef short bf16x8 __attribute__((ext_vector_type(8)));
typedef unsigned short us8 __attribute__((ext_vector_type(8)));
typedef unsigned short us4 __attribute__((ext_vector_type(4)));
typedef float f32x2 __attribute__((ext_vector_type(2)));
typedef float f32x4 __attribute__((ext_vector_type(4)));
typedef float f32x16 __attribute__((ext_vector_type(16)));
typedef unsigned int u32;
typedef unsigned int u32x4 __attribute__((ext_vector_type(4)));

__device__ __forceinline__ unsigned short f2bf(float f) {
  unsigned int u = __builtin_bit_cast(unsigned int, f);
  u += 0x7fffu + ((u >> 16) & 1u);
  return (unsigned short)(u >> 16);
}

__device__ __forceinline__ void gload16(const void* g, void* l) {
  __builtin_amdgcn_global_load_lds(
      (const __attribute__((address_space(1))) unsigned int*)g,
      (__attribute__((address_space(3))) unsigned int*)l, 16, 0, 0);
}

// ---- fused fp32 -> bf16 conversion for q_in/k_in/v_in ----
__global__ __launch_bounds__(256) void k_conv3(const float* __restrict__ i0,
                                               const float* __restrict__ i1,
                                               const float* __restrict__ i2,
                                               unsigned short* __restrict__ o0,
                                               unsigned short* __restrict__ o1,
                                               unsigned short* __restrict__ o2) {
  int bid = blockIdx.x;
  int g = bid >> 13;                 // 8192 blocks per tensor
  const float* in = g == 0 ? i0 : g == 1 ? i1 : i2;
  unsigned short* out = g == 0 ? o0 : g == 1 ? o1 : o2;
  int i = (bid & 8191) * 256 + threadIdx.x;
  float4 v = ((const float4*)in)[i];
  us4 o;
  o[0] = f2bf(v.x); o[1] = f2bf(v.y); o[2] = f2bf(v.z); o[3] = f2bf(v.w);
  ((us4*)out)[i] = o;
}

// ---- fused weight packing: g<3: [H,D,DK]->Wt[N][K]; g==3: wo [K][N]->WoT[N][K] ----
__global__ __launch_bounds__(256) void k_pack4(const float* __restrict__ wq,
                                               const float* __restrict__ wk,
                                               const float* __restrict__ wv,
                                               const float* __restrict__ wo,
                                               unsigned short* __restrict__ Wqt,
                                               unsigned short* __restrict__ Wkt,
                                               unsigned short* __restrict__ Wvt,
                                               unsigned short* __restrict__ Wot) {
  __shared__ float tl[64][65];
  int bid = blockIdx.x;
  int g = bid >> 8;
  int bl = bid & 255;
  int tid = threadIdx.x;
  if (g < 3) {
    const float* w = g == 0 ? wq : g == 1 ? wk : wv;
    unsigned short* wt = g == 0 ? Wqt : g == 1 ? Wkt : Wvt;
    int h = bl >> 4, dt = bl & 15;
#pragma unroll
    for (int i = 0; i < 16; ++i) {
      int idx = i * 256 + tid;
      int d = idx >> 6, c = idx & 63;
      tl[c][d] = w[h * 65536 + (dt * 64 + d) * 64 + c];
    }
    __syncthreads();
#pragma unroll
    for (int i = 0; i < 16; ++i) {
      int idx = i * 256 + tid;
      int c = idx >> 6, d = idx & 63;
      wt[(h * 64 + c) * 1024 + dt * 64 + d] = f2bf(tl[c][d]);
    }
  } else {
    int kt = bl >> 4, nt = bl & 15;
#pragma unroll
    for (int i = 0; i < 16; ++i) {
      int idx = i * 256 + tid;
      int k = idx >> 6, n = idx & 63;
      tl[n][k] = wo[(kt * 64 + k) * 1024 + nt * 64 + n];
    }
    __syncthreads();
#pragma unroll
    for (int i = 0; i < 16; ++i) {
      int idx = i * 256 + tid;
      int n = idx >> 6, k = idx & 63;
      Wot[(nt * 64 + n) * 1024 + kt * 64 + k] = f2bf(tl[n][k]);
    }
  }
}

// ---- bf16 GEMM body, stage-ahead double-buffered (1 barrier / K-step) ----
template<int OUT_BF16>
__device__ __forceinline__ void gemm_body(const unsigned short* __restrict__ A,
                                          const unsigned short* __restrict__ Bt,
                                          const float* __restrict__ bias,
                                          void* __restrict__ Cout, float scale,
                                          int bid) {
  __shared__ unsigned short As[2][128 * 32];
  __shared__ unsigned short Bs[2][128 * 32];
  const int tid = threadIdx.x;
  const int l = tid & 63, w = tid >> 6;
  const int wr = w >> 1, wc = w & 1;
  bid = (bid & 7) * 64 + (bid >> 3);    // XCD swizzle (512 = 8*64)
  const int bx = bid & 7;
  const int by = bid >> 3;
  const long brow = (long)by * 128;
  const int bcol = bx * 128;
  const int lr = l & 15, lg = l >> 4;
  f32x4 acc[4][4] = {};

  const char* aS0 = (const char*)(A + (brow + (tid >> 2)) * 1024 + (tid & 3) * 8);
  const char* aS1 = aS0 + 131072;
  const char* bS0 = (const char*)(Bt + (long)(bcol + (tid >> 2)) * 1024 + (tid & 3) * 8);
  const char* bS1 = bS0 + 131072;
  char* aD = (char*)&As[0][0] + w * 1024;
  char* bD = (char*)&Bs[0][0] + w * 1024;
  const char* aP = (const char*)&As[0][0] + ((wr * 64 + lr) * 32 + lg * 8) * 2;
  const char* bP = (const char*)&Bs[0][0] + ((wc * 64 + lr) * 32 + lg * 8) * 2;

  auto stage = [&](int curbuf) {
    gload16(aS0, aD + curbuf * 8192);
    gload16(aS1, aD + curbuf * 8192 + 4096);
    gload16(bS0, bD + curbuf * 8192);
    gload16(bS1, bD + curbuf * 8192 + 4096);
    aS0 += 64; aS1 += 64; bS0 += 64; bS1 += 64;
  };

  stage(0);
  for (int kk = 0; kk < 16; ++kk) {
#pragma unroll
    for (int cur = 0; cur < 2; ++cur) {
      int k0 = kk * 64 + cur * 32;
      __syncthreads();
      if (k0 + 32 < 1024) stage(cur ^ 1);
      bf16x8 af[4], bfr[4];
#pragma unroll
      for (int m = 0; m < 4; ++m)
        af[m] = *(const bf16x8*)(aP + cur * 8192 + m * 1024);
#pragma unroll
      for (int n = 0; n < 4; ++n)
        bfr[n] = *(const bf16x8*)(bP + cur * 8192 + n * 1024);
#pragma unroll
      for (int m = 0; m < 4; ++m)
#pragma unroll
        for (int n = 0; n < 4; ++n)
          acc[m][n] = __builtin_amdgcn_mfma_f32_16x16x32_bf16(af[m], bfr[n], acc[m][n], 0, 0, 0);
    }
  }

#pragma unroll
  for (int m = 0; m < 4; ++m) {
#pragma unroll
    for (int n = 0; n < 4; ++n) {
      int col = bcol + wc * 64 + n * 16 + lr;
      float bia = bias[col];
#pragma unroll
      for (int i = 0; i < 4; ++i) {
        long row = brow + wr * 64 + m * 16 + lg * 4 + i;
        float v = (acc[m][n][i] + bia) * scale;
        if (OUT_BF16) ((unsigned short*)Cout)[row * 1024 + col] = f2bf(v);
        else          ((float*)Cout)[row * 1024 + col] = v;
      }
    }
  }
}

__global__ __launch_bounds__(256) void k_gemm_qkv(const unsigned short* __restrict__ Aq,
                                                  const unsigned short* __restrict__ Ak,
                                                  const unsigned short* __restrict__ Av,
                                                  const unsigned short* __restrict__ Wqt,
                                                  const unsigned short* __restrict__ Wkt,
                                                  const unsigned short* __restrict__ Wvt,
                                                  const float* __restrict__ bq,
                                                  const float* __restrict__ bk,
                                                  const float* __restrict__ bv,
                                                  unsigned short* __restrict__ Qa,
                                                  unsigned short* __restrict__ Ka,
                                                  unsigned short* __restrict__ Va,
                                                  float qscale) {
  int g = blockIdx.x >> 9;
  int bl = blockIdx.x & 511;
  const unsigned short* A  = g == 0 ? Aq  : g == 1 ? Ak  : Av;
  const unsigned short* Bt = g == 0 ? Wqt : g == 1 ? Wkt : Wvt;
  const float* bia         = g == 0 ? bq  : g == 1 ? bk  : bv;
  unsigned short* C        = g == 0 ? Qa  : g == 1 ? Ka  : Va;
  gemm_body<1>(A, Bt, bia, C, g == 0 ? qscale : 1.0f, bl);
}

__global__ __launch_bounds__(256) void k_gemm_wo(const unsigned short* __restrict__ A,
                                                 const unsigned short* __restrict__ Bt,
                                                 const float* __restrict__ bias,
                                                 float* __restrict__ Cout) {
  gemm_body<0>(A, Bt, bias, Cout, 1.0f, blockIdx.x);
}

// ---- transpose V_all [8192,1024] -> Vt [bh][c=64][s=2048] (bf16) ----
__global__ __launch_bounds__(256) void k_transpose_v(const unsigned short* __restrict__ V,
                                                     unsigned short* __restrict__ Vt) {
  __shared__ unsigned short tile[64][72];
  int bid = blockIdx.x;
  int bh = bid >> 5, st = bid & 31;
  int b = bh >> 4, h = bh & 15;
  int tid = threadIdx.x;
#pragma unroll
  for (int i = 0; i < 2; ++i) {
    int idx = i * 256 + tid;
    int r = idx >> 3, ch = idx & 7;
    us8 v = *(const us8*)&V[((long)(b * 2048 + st * 64 + r)) * 1024 + h * 64 + ch * 8];
#pragma unroll
    for (int j = 0; j < 8; ++j) tile[ch * 8 + j][r] = v[j];
  }
  __syncthreads();
#pragma unroll
  for (int i = 0; i < 2; ++i) {
    int idx = i * 256 + tid;
    int c = idx >> 3, ch = idx & 7;
    us8 v;
#pragma unroll
    for (int j = 0; j < 8; ++j) v[j] = tile[c][ch * 8 + j];
    *(us8*)&Vt[(long)bh * 131072 + (long)c * 2048 + st * 64 + ch * 8] = v;
  }
}

// ---- flash attention v7: cross-tile software pipeline (att[2]) ----
// 32 q/wave, 1024 blocks. K/V TRIPLE-buffered in LDS (48KB): iteration t
// computes QK(t) -> score-set C while softmax(t-1)+PV(t-1) run from set P
// (ping-pong via x2 unroll, no copies). stage(t+1) overwrites buf[t-2],
// whose reads finished before this iteration's barrier. One barrier/tile.
// LDS: K buf b @ b*8192 (0..24575), V buf b @ 24576+b*8192 (24576..49151).
__global__ __launch_bounds__(256) void k_attn7(const unsigned short* __restrict__ Q,
                                               const unsigned short* __restrict__ K,
                                               const unsigned short* __restrict__ Vt,
                                               unsigned short* __restrict__ AO) {
  __shared__ unsigned short KV[3 * 8192];      // 48 KiB: K bufs then V bufs
  __shared__ float Li[4][32];
  const int tid = threadIdx.x;
  const int l = tid & 63, w = tid >> 6;
  const int l31 = l & 31, hi = l >> 5;
  int bid0 = blockIdx.x;
  int bid = (bid0 & 7) * 128 + (bid0 >> 3);  // XCD swizzle (1024 = 8*128)
  const int bh = bid >> 4, qt0 = bid & 15;
  const int b = bh >> 4, h = bh & 15;
  const unsigned short* Qb = Q + (long)b * 2048 * 1024 + h * 64;
  const unsigned short* Kb = K + (long)b * 2048 * 1024 + h * 64;
  const unsigned short* Vb = Vt + (long)bh * 131072;   // [64 c][2048 s]
  const int qbase = qt0 * 128 + w * 32;

  // persistent Q fragments (B-operand; col=q=l31)
  bf16x8 qf[4];
#pragma unroll
  for (int c = 0; c < 4; ++c)
    qf[c] = *(const bf16x8*)&Qb[(long)(qbase + l31) * 1024 + c * 16 + hi * 8];

  f32x16 acc0 = {}, acc1 = {};
  f32x16 z16 = {};
  f32x16 sA0, sA1, sB0, sB1;
  float l0 = 0.f, l1 = 0.f, l2 = 0.f, l3 = 0.f;
  const int rsw = (l31 & 7) << 4;

  // per-lane LDS fragment bases (add runtime buffer offset + imm at use)
  const char* pb[4];
#pragma unroll
  for (int c = 0; c < 4; ++c)
    pb[c] = (const char*)&KV[0] + l31 * 128 + ((c * 32 + hi * 16) ^ rsw);

  // staging pointers (pre-swizzled global source, linear LDS dest)
  const int sch = tid & 7, srw = tid >> 3;
  const int ssw = (sch * 16) ^ ((srw & 7) << 4);
  const char* ks0 = (const char*)Kb + (long)srw * 2048 + ssw;   // 64 rows x 128B
  const char* ks1 = ks0 + 65536;                                 // rows 32..63
  const char* vs0 = (const char*)Vb + (long)srw * 4096 + ssw;   // 32 c-rows x 128B
  const char* vs1 = vs0 + 131072;                                // c 32..63
  char* dK = (char*)&KV[0] + w * 1024;          // + lane*16 implicit
  char* dV = dK + 24576;

  auto stage = [&](int buf) {
    gload16(ks0, dK + buf * 8192);
    gload16(ks1, dK + buf * 8192 + 4096);
    gload16(vs0, dV + buf * 8192);
    gload16(vs1, dV + buf * 8192 + 4096);
    ks0 += 131072; ks1 += 131072;    // next 64 t-rows
    vs0 += 128;    vs1 += 128;       // next 64 t-columns
  };

  int bufp = 2, bufc = 0, bufs = 1;   // prev / current / stage-target
  auto rotate = [&]() { int t = bufp; bufp = bufc; bufc = bufs; bufs = t; };

  // QK of current tile into (c0,c1)
  auto QK = [&](f32x16& c0, f32x16& c1) {
    int ko = bufc * 8192;
    bf16x8 kf[4];
#pragma unroll
    for (int c = 0; c < 4; ++c) kf[c] = *(const bf16x8*)(pb[c] + ko);
    c0 = __builtin_amdgcn_mfma_f32_32x32x16_bf16(kf[0], qf[0], z16, 0, 0, 0);
#pragma unroll
    for (int c = 1; c < 4; ++c)
      c0 = __builtin_amdgcn_mfma_f32_32x32x16_bf16(kf[c], qf[c], c0, 0, 0, 0);
#pragma unroll
    for (int c = 0; c < 4; ++c) kf[c] = *(const bf16x8*)(pb[c] + ko + 4096);
    c1 = __builtin_amdgcn_mfma_f32_32x32x16_bf16(kf[0], qf[0], z16, 0, 0, 0);
#pragma unroll
    for (int c = 1; c < 4; ++c)
      c1 = __builtin_amdgcn_mfma_f32_32x32x16_bf16(kf[c], qf[c], c1, 0, 0, 0);
  };

  // softmax(prev scores) -> pa[4], then PV from V buf bufp
  auto SMPV = [&](const f32x16& p0, const f32x16& p1) {
    bf16x8 pa[4];
#pragma unroll
    for (int h2 = 0; h2 < 2; ++h2) {
      const f32x16& s = h2 == 0 ? p0 : p1;
      float p[16];
#pragma unroll
      for (int r = 0; r < 16; ++r) p[r] = __builtin_amdgcn_exp2f(s[r]);
      l0 += p[0] + p[4] + p[8] + p[12];
      l1 += p[1] + p[5] + p[9] + p[13];
      l2 += p[2] + p[6] + p[10] + p[14];
      l3 += p[3] + p[7] + p[11] + p[15];
      u32 wg[4][2];
#pragma unroll
      for (int g = 0; g < 4; ++g) {
        asm("v_cvt_pk_bf16_f32 %0, %1, %2" : "=v"(wg[g][0]) : "v"(p[4 * g]), "v"(p[4 * g + 1]));
        asm("v_cvt_pk_bf16_f32 %0, %1, %2" : "=v"(wg[g][1]) : "v"(p[4 * g + 2]), "v"(p[4 * g + 3]));
      }
#pragma unroll
      for (int sub = 0; sub < 2; ++sub) {
        u32 x0 = wg[2 * sub][0], y0 = wg[2 * sub + 1][0];
        u32 x1 = wg[2 * sub][1], y1 = wg[2 * sub + 1][1];
        asm("v_permlane32_swap_b32 %0, %1" : "+v"(x0), "+v"(y0));
        asm("v_permlane32_swap_b32 %0, %1" : "+v"(x1), "+v"(y1));
        u32x4 fw; fw[0] = x0; fw[1] = x1; fw[2] = y0; fw[3] = y1;
        pa[h2 * 2 + sub] = __builtin_bit_cast(bf16x8, fw);
      }
    }
    int vo = 24576 + bufp * 8192;
#pragma unroll
    for (int ck = 0; ck < 4; ++ck) {
      bf16x8 vf0 = *(const bf16x8*)(pb[ck] + vo);
      bf16x8 vf1 = *(const bf16x8*)(pb[ck] + vo + 4096);
      acc0 = __builtin_amdgcn_mfma_f32_32x32x16_bf16(pa[ck], vf0, acc0, 0, 0, 0);
      acc1 = __builtin_amdgcn_mfma_f32_32x32x16_bf16(pa[ck], vf1, acc1, 0, 0, 0);
    }
  };

  // prologue: tile 0
  stage(0);
  __syncthreads();
  QK(sA0, sA1);
  stage(1);          // bufs == 1
  rotate();          // bufp=0 bufc=1 bufs=2

  // main: tiles 1..30 as 15 ping-pong pairs
  for (int j = 0; j < 15; ++j) {
    // t = 2j+1: write B, finish A
    __syncthreads();
    QK(sB0, sB1);
    stage(bufs);
    SMPV(sA0, sA1);
    rotate();
    // t = 2j+2: write A, finish B
    __syncthreads();
    QK(sA0, sA1);
    stage(bufs);
    SMPV(sB0, sB1);
    rotate();
  }
  // t = 31: write B, finish A, no stage
  __syncthreads();
  QK(sB0, sB1);
  SMPV(sA0, sA1);
  rotate();          // bufp now = buf of tile 31
  // epilogue: finish tile 31
  SMPV(sB0, sB1);

  // final reduce + store
  float li = l0 + l1 + l2 + l3;
  li += __shfl_xor(li, 32);
  if (hi == 0) Li[w][l31] = 1.f / li;
  __syncthreads();
#pragma unroll
  for (int ct = 0; ct < 2; ++ct) {
    const f32x16& a = ct == 0 ? acc0 : acc1;
#pragma unroll
    for (int r = 0; r < 16; ++r) {
      int qrow = (r & 3) + 8 * (r >> 2) + 4 * hi;
      float inv = Li[w][qrow];
      long row = (long)b * 2048 + qbase + qrow;
      int col = h * 64 + ct * 32 + l31;
      AO[row * 1024 + col] = f2bf(a[r] * inv);
    }
  }
}

extern "C" void kernel_launch(void* const* d_in, const int* in_sizes, int n_in,
                              void* d_out, int out_size, void* d_ws, size_t ws_size,
                              hipStream_t stream) {
  (void)in_sizes; (void)n_in; (void)out_size; (void)ws_size;
  const float* q_in = (const float*)d_in[0];
  const float* k_in = (const float*)d_in[1];
  const float* v_in = (const float*)d_in[2];
  const float* wq   = (const float*)d_in[3];
  const float* bq   = (const float*)d_in[4];
  const float* wk   = (const float*)d_in[5];
  const float* bk   = (const float*)d_in[6];
  const float* wv   = (const float*)d_in[7];
  const float* bv   = (const float*)d_in[8];
  const float* wo   = (const float*)d_in[9];
  const float* bo   = (const float*)d_in[10];

  char* ws = (char*)d_ws;
  const size_t SZA = (size_t)8192 * 1024 * 2;   // 16 MiB per [8192,1024] bf16
  unsigned short* Aq  = (unsigned short*)(ws);
  unsigned short* Ak  = (unsigned short*)(ws + SZA);
  unsigned short* Av  = (unsigned short*)(ws + 2 * SZA);
  unsigned short* Qa  = (unsigned short*)(ws + 3 * SZA);
  unsigned short* Ka  = (unsigned short*)(ws + 4 * SZA);
  unsigned short* Va  = (unsigned short*)(ws + 5 * SZA);
  unsigned short* Wqt = (unsigned short*)(ws + 6 * SZA);
  unsigned short* Wkt = Wqt + 1048576;
  unsigned short* Wvt = Wkt + 1048576;
  unsigned short* Wot = Wvt + 1048576;
  unsigned short* Vtr = Ak;   // Ak dead after K projection GEMM
  unsigned short* AO  = Aq;   // Aq dead after Q projection GEMM

  const float QSCALE = 0.1803368801111204f;  // log2(e)/8 -> exp2-domain softmax

  k_conv3<<<24576, 256, 0, stream>>>(q_in, k_in, v_in, Aq, Ak, Av);
  k_pack4<<<1024, 256, 0, stream>>>(wq, wk, wv, wo, Wqt, Wkt, Wvt, Wot);
  k_gemm_qkv<<<1536, 256, 0, stream>>>(Aq, Ak, Av, Wqt, Wkt, Wvt, bq, bk, bv,
                                       Qa, Ka, Va, QSCALE);
  k_transpose_v<<<2048, 256, 0, stream>>>(Va, Vtr);
  k_attn7<<<1024, 256, 0, stream>>>(Qa, Ka, Vtr, AO);
  k_gemm_wo<<<512, 256, 0, stream>>>(AO, Wot, bo, (float*)d_out);
}